// Round 1
// baseline (906.952 us; speedup 1.0000x reference)
//
#include <hip/hip_runtime.h>
#include <cstdint>
#include <cstddef>

#define TPB 256

// ---------------- CSR build ----------------

__global__ void count_deg(const int* __restrict__ dst, int* __restrict__ deg, int e) {
  int i = blockIdx.x * TPB + threadIdx.x;
  if (i < e) atomicAdd(&deg[dst[i]], 1);
}

__global__ void scan1(const int* __restrict__ deg, int* __restrict__ off,
                      int* __restrict__ bsums, int n) {
  __shared__ int s[TPB];
  int tx = threadIdx.x;
  int i = blockIdx.x * TPB + tx;
  int v = (i < n) ? deg[i] : 0;
  s[tx] = v;
  __syncthreads();
  for (int d = 1; d < TPB; d <<= 1) {
    int t = (tx >= d) ? s[tx - d] : 0;
    __syncthreads();
    s[tx] += t;
    __syncthreads();
  }
  if (i < n) off[i] = s[tx] - v;            // exclusive within block
  if (tx == TPB - 1) bsums[blockIdx.x] = s[tx];
}

__global__ void scan2(int* __restrict__ bsums, int nb) {
  __shared__ int s[TPB];
  __shared__ int carry;
  int tx = threadIdx.x;
  if (tx == 0) carry = 0;
  __syncthreads();
  for (int base = 0; base < nb; base += TPB) {
    int i = base + tx;
    int v = (i < nb) ? bsums[i] : 0;
    s[tx] = v;
    __syncthreads();
    for (int d = 1; d < TPB; d <<= 1) {
      int t = (tx >= d) ? s[tx - d] : 0;
      __syncthreads();
      s[tx] += t;
      __syncthreads();
    }
    int c = carry;
    if (i < nb) bsums[i] = c + s[tx] - v;   // exclusive across blocks
    __syncthreads();
    if (tx == TPB - 1) carry = c + s[tx];
    __syncthreads();
  }
}

__global__ void scan3(int* __restrict__ off, int* __restrict__ pos,
                      const int* __restrict__ bsums, int n, int e) {
  int i = blockIdx.x * TPB + threadIdx.x;
  if (i < n) {
    int o = off[i] + bsums[blockIdx.x];
    off[i] = o;
    pos[i] = o;
  }
  if (i == 0) off[n] = e;
}

__global__ void fill_csr(const int* __restrict__ src, const int* __restrict__ dst,
                         int* __restrict__ pos, int* __restrict__ col, int e) {
  int i = blockIdx.x * TPB + threadIdx.x;
  if (i < e) {
    int d = dst[i];
    int p = atomicAdd(&pos[d], 1);
    col[p] = src[i];
  }
}

// ---------------- mean aggregation: one wave per node ----------------
// 128 features -> 64 lanes x float2, each neighbor row = 512B coalesced read.

__global__ void aggregate(const float* __restrict__ X, const int* __restrict__ off,
                          const int* __restrict__ col, float* __restrict__ out, int n) {
  int node = (blockIdx.x * TPB + threadIdx.x) >> 6;
  int lane = threadIdx.x & 63;
  if (node >= n) return;
  int s0 = off[node], s1 = off[node + 1];
  float ax = 0.f, ay = 0.f;
  for (int e = s0; e < s1; ++e) {
    int s = col[e];
    const float2 v = *(const float2*)(X + (size_t)s * 128 + lane * 2);
    ax += v.x;
    ay += v.y;
  }
  float inv = (s1 > s0) ? 1.0f / (float)(s1 - s0) : 0.f;
  float2 o;
  o.x = ax * inv;
  o.y = ay * inv;
  *(float2*)(out + (size_t)node * 128 + lane * 2) = o;
}

// ---------------- fused concat-GEMM + bias + ELU (+ dropout) ----------------
// out[i,f] = elu( sum_k A1[i,k]*Wa[k,f] + A2[i,k]*Wb[k,f] + bias[f] ) [* keep]
// Block: 64 rows, all NF features. A-tile [64 x 256] in 64 KiB LDS.
// Thread = (4-feature strip) x (NF/16 rows): fp32 register accumulators.

__device__ __forceinline__ float elu_f(float z) { return z > 0.f ? z : expm1f(z); }

template <int NF, bool DROP>
__global__ __launch_bounds__(256) void gemm_fused(
    const float* __restrict__ A1, const float* __restrict__ A2,
    const float* __restrict__ Wa, const float* __restrict__ Wb,
    const float* __restrict__ bias, const float* __restrict__ dropu,
    float* __restrict__ out, int n) {
  constexpr int LDA = 256;        // floats per LDS row (K = 128+128)
  constexpr int FT = NF / 4;      // feature-threads (each covers 4 cols)
  constexpr int RT = NF / 16;     // rows per thread; (256/FT) groups * RT = 64 rows
  __shared__ float At[64 * LDA];  // 64 KiB

  int tid = threadIdx.x;
  int row0 = blockIdx.x * 64;

  // stage 64 rows x (A1 | A2) into LDS, coalesced float4
#pragma unroll
  for (int t = 0; t < 16; ++t) {
    int idx = t * 256 + tid;   // float4 slot: 64 rows * 64 slots
    int r = idx >> 6;
    int c4 = idx & 63;
    int row = row0 + r;
    float4 v = make_float4(0.f, 0.f, 0.f, 0.f);
    if (row < n) {
      const float* p = (c4 < 32) ? (A1 + (size_t)row * 128 + c4 * 4)
                                 : (A2 + (size_t)row * 128 + (c4 - 32) * 4);
      v = *(const float4*)p;
    }
    *(float4*)(At + r * LDA + c4 * 4) = v;
  }
  __syncthreads();

  int fq = tid % FT;
  int f = fq * 4;
  int rg = tid / FT;
  float4 acc[RT];
#pragma unroll
  for (int r = 0; r < RT; ++r) acc[r] = make_float4(0.f, 0.f, 0.f, 0.f);
  const float* Atp = At + (rg * RT) * LDA;

#pragma unroll
  for (int half = 0; half < 2; ++half) {
    const float* W = half ? Wb : Wa;
    const float* Ath = Atp + half * 128;
    for (int k = 0; k < 128; k += 4) {
      float4 w0 = *(const float4*)(W + (k + 0) * NF + f);
      float4 w1 = *(const float4*)(W + (k + 1) * NF + f);
      float4 w2 = *(const float4*)(W + (k + 2) * NF + f);
      float4 w3 = *(const float4*)(W + (k + 3) * NF + f);
#pragma unroll
      for (int r = 0; r < RT; ++r) {
        float4 a = *(const float4*)(Ath + r * LDA + k);
        acc[r].x += a.x * w0.x + a.y * w1.x + a.z * w2.x + a.w * w3.x;
        acc[r].y += a.x * w0.y + a.y * w1.y + a.z * w2.y + a.w * w3.y;
        acc[r].z += a.x * w0.z + a.y * w1.z + a.z * w2.z + a.w * w3.z;
        acc[r].w += a.x * w0.w + a.y * w1.w + a.z * w2.w + a.w * w3.w;
      }
    }
  }

  float4 bb = *(const float4*)(bias + f);
#pragma unroll
  for (int r = 0; r < RT; ++r) {
    int row = row0 + rg * RT + r;
    if (row >= n) continue;
    float4 v;
    v.x = elu_f(acc[r].x + bb.x);
    v.y = elu_f(acc[r].y + bb.y);
    v.z = elu_f(acc[r].z + bb.z);
    v.w = elu_f(acc[r].w + bb.w);
    if (DROP) {
      float4 u = *(const float4*)(dropu + (size_t)row * 128 + f);
      v.x *= (u.x >= 0.2f) ? 1.25f : 0.f;
      v.y *= (u.y >= 0.2f) ? 1.25f : 0.f;
      v.z *= (u.z >= 0.2f) ? 1.25f : 0.f;
      v.w *= (u.w >= 0.2f) ? 1.25f : 0.f;
    }
    *(float4*)(out + (size_t)row * NF + f) = v;
  }
}

// ---------------- launch ----------------

extern "C" void kernel_launch(void* const* d_in, const int* in_sizes, int n_in,
                              void* d_out, int out_size, void* d_ws, size_t ws_size,
                              hipStream_t stream) {
  const float* x = (const float*)d_in[0];
  const int* ei = (const int*)d_in[1];
  const float* dropu = (const float*)d_in[2];
  const float* W1l = (const float*)d_in[3];
  const float* W1r = (const float*)d_in[4];
  const float* b1 = (const float*)d_in[5];
  const float* W2l = (const float*)d_in[6];
  const float* W2r = (const float*)d_in[7];
  const float* b2 = (const float*)d_in[8];

  int n = in_sizes[0] / 128;
  int e = in_sizes[1] / 2;
  const int* src = ei;       // edge_index[0]
  const int* dst = ei + e;   // edge_index[1]
  float* out = (float*)d_out;

  char* w = (char*)d_ws;
  auto alloc = [&](size_t bytes) -> char* {
    char* p = w;
    w += (bytes + 255) & ~(size_t)255;
    return p;
  };
  int nb = (n + TPB - 1) / TPB;
  int* off = (int*)alloc((size_t)(n + 1) * sizeof(int));
  int* pos = (int*)alloc((size_t)n * sizeof(int));
  int* deg = (int*)alloc((size_t)n * sizeof(int));
  int* bsums = (int*)alloc((size_t)nb * sizeof(int));
  int* col = (int*)alloc((size_t)e * sizeof(int));
  float* agg = (float*)alloc((size_t)n * 128 * sizeof(float));
  float* h = (float*)alloc((size_t)n * 128 * sizeof(float));

  hipMemsetAsync(deg, 0, (size_t)n * sizeof(int), stream);

  int gE = (e + TPB - 1) / TPB;
  count_deg<<<gE, TPB, 0, stream>>>(dst, deg, e);
  scan1<<<nb, TPB, 0, stream>>>(deg, off, bsums, n);
  scan2<<<1, TPB, 0, stream>>>(bsums, nb);
  scan3<<<nb, TPB, 0, stream>>>(off, pos, bsums, n, e);
  fill_csr<<<gE, TPB, 0, stream>>>(src, dst, pos, col, e);

  int gN = (n + 3) / 4;      // 4 nodes (waves) per block
  int gR = (n + 63) / 64;    // 64 rows per gemm block

  // layer 1: h = dropout(elu([agg|x] @ [W1l;W1r] + b1))
  aggregate<<<gN, TPB, 0, stream>>>(x, off, col, agg, n);
  gemm_fused<128, true><<<gR, TPB, 0, stream>>>(agg, x, W1l, W1r, b1, dropu, h, n);

  // layer 2: out = elu([agg2|h] @ [W2l;W2r] + b2)
  aggregate<<<gN, TPB, 0, stream>>>(h, off, col, agg, n);
  gemm_fused<64, false><<<gR, TPB, 0, stream>>>(agg, h, W2l, W2r, b2, nullptr, out, n);
}

// Round 2
// 586.256 us; speedup vs baseline: 1.5470x; 1.5470x over previous
//
#include <hip/hip_runtime.h>
#include <cstdint>
#include <cstddef>

#define TPB 256

typedef short bf16x8 __attribute__((ext_vector_type(8)));
typedef float f32x4 __attribute__((ext_vector_type(4)));

__device__ __forceinline__ unsigned short f2bf(float f) {
  unsigned int u = __float_as_uint(f);
  unsigned int r = (u + 0x7fffu + ((u >> 16) & 1u)) >> 16;  // RNE
  return (unsigned short)r;
}
__device__ __forceinline__ float bf2f(unsigned short h) {
  return __uint_as_float(((unsigned int)h) << 16);
}

// ---------------- CSR build ----------------

__global__ void count_deg(const int* __restrict__ dst, int* __restrict__ deg, int e) {
  int i = blockIdx.x * TPB + threadIdx.x;
  if (i < e) atomicAdd(&deg[dst[i]], 1);
}

__global__ void scan1(const int* __restrict__ deg, int* __restrict__ off,
                      int* __restrict__ bsums, int n) {
  __shared__ int s[TPB];
  int tx = threadIdx.x;
  int i = blockIdx.x * TPB + tx;
  int v = (i < n) ? deg[i] : 0;
  s[tx] = v;
  __syncthreads();
  for (int d = 1; d < TPB; d <<= 1) {
    int t = (tx >= d) ? s[tx - d] : 0;
    __syncthreads();
    s[tx] += t;
    __syncthreads();
  }
  if (i < n) off[i] = s[tx] - v;
  if (tx == TPB - 1) bsums[blockIdx.x] = s[tx];
}

__global__ void scan2(int* __restrict__ bsums, int nb) {
  __shared__ int s[TPB];
  __shared__ int carry;
  int tx = threadIdx.x;
  if (tx == 0) carry = 0;
  __syncthreads();
  for (int base = 0; base < nb; base += TPB) {
    int i = base + tx;
    int v = (i < nb) ? bsums[i] : 0;
    s[tx] = v;
    __syncthreads();
    for (int d = 1; d < TPB; d <<= 1) {
      int t = (tx >= d) ? s[tx - d] : 0;
      __syncthreads();
      s[tx] += t;
      __syncthreads();
    }
    int c = carry;
    if (i < nb) bsums[i] = c + s[tx] - v;
    __syncthreads();
    if (tx == TPB - 1) carry = c + s[tx];
    __syncthreads();
  }
}

__global__ void scan3(int* __restrict__ off, int* __restrict__ pos,
                      const int* __restrict__ bsums, int n, int e) {
  int i = blockIdx.x * TPB + threadIdx.x;
  if (i < n) {
    int o = off[i] + bsums[blockIdx.x];
    off[i] = o;
    pos[i] = o;
  }
  if (i == 0) off[n] = e;
}

__global__ void fill_csr(const int* __restrict__ src, const int* __restrict__ dst,
                         int* __restrict__ pos, int* __restrict__ col, int e) {
  int i = blockIdx.x * TPB + threadIdx.x;
  if (i < e) {
    int d = dst[i];
    int p = atomicAdd(&pos[d], 1);
    col[p] = src[i];
  }
}

// ---------------- converts ----------------

__global__ void f32_to_bf16_v4(const float* __restrict__ in, unsigned short* __restrict__ out,
                               int n4) {
  int i = blockIdx.x * TPB + threadIdx.x;
  if (i >= n4) return;
  float4 v = ((const float4*)in)[i];
  ushort4 o;
  o.x = f2bf(v.x); o.y = f2bf(v.y); o.z = f2bf(v.z); o.w = f2bf(v.w);
  ((ushort4*)out)[i] = o;
}

// Wt[nn][k] (k=0..255) = k<128 ? Wl[k][nn] : Wr[k-128][nn], bf16
template <int NF>
__global__ void build_wt(const float* __restrict__ Wl, const float* __restrict__ Wr,
                         unsigned short* __restrict__ Wt) {
  int idx = blockIdx.x * TPB + threadIdx.x;
  if (idx >= NF * 256) return;
  int nn = idx >> 8;
  int k = idx & 255;
  float v = (k < 128) ? Wl[k * NF + nn] : Wr[(k - 128) * NF + nn];
  Wt[idx] = f2bf(v);
}

// ---------------- mean aggregation (bf16 in/out): one wave per node ----------------
// 128 feats -> 64 lanes x bf16x2 (1 dword). Neighbor row = 256 B coalesced.

__global__ void aggregate_bf(const unsigned short* __restrict__ X,
                             const int* __restrict__ off, const int* __restrict__ col,
                             unsigned short* __restrict__ out, int n) {
  int node = (blockIdx.x * TPB + threadIdx.x) >> 6;
  int lane = threadIdx.x & 63;
  if (node >= n) return;
  int s0 = off[node], s1 = off[node + 1];
  float ax = 0.f, ay = 0.f;
  int e = s0;
  for (; e + 4 <= s1; e += 4) {
    int c0 = col[e], c1 = col[e + 1], c2 = col[e + 2], c3 = col[e + 3];
    unsigned int v0 = *(const unsigned int*)(X + (size_t)c0 * 128 + lane * 2);
    unsigned int v1 = *(const unsigned int*)(X + (size_t)c1 * 128 + lane * 2);
    unsigned int v2 = *(const unsigned int*)(X + (size_t)c2 * 128 + lane * 2);
    unsigned int v3 = *(const unsigned int*)(X + (size_t)c3 * 128 + lane * 2);
    ax += bf2f(v0 & 0xffff) + bf2f(v1 & 0xffff) + bf2f(v2 & 0xffff) + bf2f(v3 & 0xffff);
    ay += bf2f(v0 >> 16) + bf2f(v1 >> 16) + bf2f(v2 >> 16) + bf2f(v3 >> 16);
  }
  for (; e < s1; ++e) {
    int c = col[e];
    unsigned int v = *(const unsigned int*)(X + (size_t)c * 128 + lane * 2);
    ax += bf2f(v & 0xffff);
    ay += bf2f(v >> 16);
  }
  float inv = (s1 > s0) ? 1.0f / (float)(s1 - s0) : 0.f;
  unsigned int o = ((unsigned int)f2bf(ay * inv) << 16) | f2bf(ax * inv);
  *(unsigned int*)(out + (size_t)node * 128 + lane * 2) = o;
}

// ---------------- MFMA GEMM: C[n x NF] = [A1|A2][n x 256] @ Wt^T + bias, fused epilogue
// Block: 128 rows x NF cols, 4 waves (2x2), wave tile 64 x (NT*16).
// K-loop: 4 chunks of BK=64. LDS pad +8 bf16 per row (stride 72) -> 2-way-free frag reads.
// MFMA 16x16x32 bf16 layouts (HW-verified, learn_hip m89/m120):
//   A: m=lane&15, k=(lane>>4)*8+j ; B: n=lane&15, k=(lane>>4)*8+j ;
//   D: col=lane&15, row=(lane>>4)*4+reg.

template <int NT, bool DROP, bool OUT32>
__global__ __launch_bounds__(256) void gemm_mfma(
    const unsigned short* __restrict__ A1, const unsigned short* __restrict__ A2,
    const unsigned short* __restrict__ Wt, const float* __restrict__ bias,
    const float* __restrict__ dropu, unsigned short* __restrict__ outb,
    float* __restrict__ outf, int n) {
  constexpr int NF = 32 * NT;           // block N = output dim
  constexpr int SA = 72;                // padded LDS row stride (bf16)
  __shared__ __align__(16) unsigned short sA[128 * SA];
  __shared__ __align__(16) unsigned short sB[NF * SA];

  int tid = threadIdx.x;
  int row0 = blockIdx.x * 128;
  int lane = tid & 63;
  int wid = tid >> 6;
  int wm = wid >> 1, wn = wid & 1;
  int lq = lane & 15, q = lane >> 4;

  f32x4 acc[4][NT];
#pragma unroll
  for (int i = 0; i < 4; ++i)
#pragma unroll
    for (int j = 0; j < NT; ++j) acc[i][j] = (f32x4)(0.f);

#pragma unroll
  for (int c = 0; c < 4; ++c) {
    const unsigned short* Asrc = (c < 2) ? A1 : A2;
    int koff = (c & 1) * 64;
    __syncthreads();
    // stage A chunk: 128 rows x 64 cols bf16, 16B per thread-slot
#pragma unroll
    for (int t = 0; t < 4; ++t) {
      int s = t * 256 + tid;
      int r = s >> 3, c8 = s & 7;
      int row = row0 + r;
      uint4 v = make_uint4(0u, 0u, 0u, 0u);
      if (row < n) v = *(const uint4*)(Asrc + (size_t)row * 128 + koff + c8 * 8);
      *(uint4*)(&sA[r * SA + c8 * 8]) = v;
    }
    // stage B chunk: NF rows x 64 cols from Wt[NF x 256]
#pragma unroll
    for (int t = 0; t < NT; ++t) {
      int s = t * 256 + tid;
      int r = s >> 3, c8 = s & 7;
      uint4 v = *(const uint4*)(Wt + (size_t)r * 256 + c * 64 + c8 * 8);
      *(uint4*)(&sB[r * SA + c8 * 8]) = v;
    }
    __syncthreads();

#pragma unroll
    for (int ks = 0; ks < 2; ++ks) {
      int kofs = ks * 32;
      bf16x8 a[4], b[NT];
#pragma unroll
      for (int i = 0; i < 4; ++i)
        a[i] = *(const bf16x8*)(&sA[(wm * 64 + i * 16 + lq) * SA + kofs + q * 8]);
#pragma unroll
      for (int j = 0; j < NT; ++j)
        b[j] = *(const bf16x8*)(&sB[(wn * NT * 16 + j * 16 + lq) * SA + kofs + q * 8]);
#pragma unroll
      for (int i = 0; i < 4; ++i)
#pragma unroll
        for (int j = 0; j < NT; ++j)
          acc[i][j] = __builtin_amdgcn_mfma_f32_16x16x32_bf16(a[i], b[j], acc[i][j], 0, 0, 0);
    }
  }

  // epilogue: bias + ELU (+ dropout), store bf16 or f32
#pragma unroll
  for (int j = 0; j < NT; ++j) {
    int colg = wn * NT * 16 + j * 16 + lq;
    float bv = bias[colg];
#pragma unroll
    for (int i = 0; i < 4; ++i) {
      int rbase = row0 + wm * 64 + i * 16 + q * 4;
#pragma unroll
      for (int r = 0; r < 4; ++r) {
        int row = rbase + r;
        if (row >= n) continue;
        float v = acc[i][j][r] + bv;
        v = (v > 0.f) ? v : expm1f(v);
        if (DROP) {
          float u = dropu[(size_t)row * 128 + colg];
          v *= (u >= 0.2f) ? 1.25f : 0.f;
        }
        if (OUT32) outf[(size_t)row * NF + colg] = v;
        else outb[(size_t)row * NF + colg] = f2bf(v);
      }
    }
  }
}

// ---------------- launch ----------------

extern "C" void kernel_launch(void* const* d_in, const int* in_sizes, int n_in,
                              void* d_out, int out_size, void* d_ws, size_t ws_size,
                              hipStream_t stream) {
  const float* x = (const float*)d_in[0];
  const int* ei = (const int*)d_in[1];
  const float* dropu = (const float*)d_in[2];
  const float* W1l = (const float*)d_in[3];
  const float* W1r = (const float*)d_in[4];
  const float* b1 = (const float*)d_in[5];
  const float* W2l = (const float*)d_in[6];
  const float* W2r = (const float*)d_in[7];
  const float* b2 = (const float*)d_in[8];

  int n = in_sizes[0] / 128;
  int e = in_sizes[1] / 2;
  const int* src = ei;
  const int* dst = ei + e;
  float* out = (float*)d_out;

  char* w = (char*)d_ws;
  auto alloc = [&](size_t bytes) -> char* {
    char* p = w;
    w += (bytes + 255) & ~(size_t)255;
    return p;
  };
  int nb = (n + TPB - 1) / TPB;
  int* off = (int*)alloc((size_t)(n + 1) * sizeof(int));
  int* pos = (int*)alloc((size_t)n * sizeof(int));
  int* deg = (int*)alloc((size_t)n * sizeof(int));
  int* bsums = (int*)alloc((size_t)nb * sizeof(int));
  int* col = (int*)alloc((size_t)e * sizeof(int));
  unsigned short* xb = (unsigned short*)alloc((size_t)n * 128 * 2);
  unsigned short* hb = (unsigned short*)alloc((size_t)n * 128 * 2);
  unsigned short* aggb = (unsigned short*)alloc((size_t)n * 128 * 2);
  unsigned short* Wt1 = (unsigned short*)alloc(128 * 256 * 2);
  unsigned short* Wt2 = (unsigned short*)alloc(64 * 256 * 2);

  hipMemsetAsync(deg, 0, (size_t)n * sizeof(int), stream);

  int gE = (e + TPB - 1) / TPB;
  count_deg<<<gE, TPB, 0, stream>>>(dst, deg, e);
  scan1<<<nb, TPB, 0, stream>>>(deg, off, bsums, n);
  scan2<<<1, TPB, 0, stream>>>(bsums, nb);
  scan3<<<nb, TPB, 0, stream>>>(off, pos, bsums, n, e);
  fill_csr<<<gE, TPB, 0, stream>>>(src, dst, pos, col, e);

  // converts
  int n4 = n * 128 / 4;
  f32_to_bf16_v4<<<(n4 + TPB - 1) / TPB, TPB, 0, stream>>>(x, xb, n4);
  build_wt<128><<<(128 * 256 + TPB - 1) / TPB, TPB, 0, stream>>>(W1l, W1r, Wt1);
  build_wt<64><<<(64 * 256 + TPB - 1) / TPB, TPB, 0, stream>>>(W2l, W2r, Wt2);

  int gN = (n + 3) / 4;       // aggregate: 4 waves/block, 1 node/wave
  int gR = (n + 127) / 128;   // gemm: 128 rows/block

  // layer 1: hb = dropout(elu([agg|x] @ [W1l;W1r] + b1))  (bf16)
  aggregate_bf<<<gN, TPB, 0, stream>>>(xb, off, col, aggb, n);
  gemm_mfma<4, true, false><<<gR, TPB, 0, stream>>>(aggb, xb, Wt1, b1, dropu, hb, nullptr, n);

  // layer 2: out = elu([agg2|h] @ [W2l;W2r] + b2)  (fp32 out)
  aggregate_bf<<<gN, TPB, 0, stream>>>(hb, off, col, aggb, n);
  gemm_mfma<2, false, true><<<gR, TPB, 0, stream>>>(aggb, hb, Wt2, b2, nullptr, nullptr, out, n);
}